// Round 5
// baseline (25122.313 us; speedup 1.0000x reference)
//
#include <hip/hip_runtime.h>

typedef unsigned short u16;
typedef unsigned int u32;
typedef unsigned long long u64;
typedef __attribute__((ext_vector_type(8))) short bf16x8;   // 8 bf16 (4 VGPRs)
typedef __attribute__((ext_vector_type(4))) float f32x4;

#define T_STEPS 1024
#define E_SZ 128
#define U_SZ 256

#define NG 16   // batch groups
#define NS 16   // unit slices (wgs per group)
#define MB 16   // batch rows per group (MFMA M)
#define HS 264  // padded LDS row stride for K=256
#define EPAD 136 // padded LDS row stride for K=128

// LDS byte offsets (all 16B aligned)
#define OFF_W0T 0                    // 64*EPAD*2 = 17408
#define OFF_R0T 17408                // 64*HS*2   = 33792
#define OFF_W1T 51200                // 33792
#define OFF_R1T 84992                // 33792
#define OFF_H0  118784               // 16*HS*2   = 8448
#define OFF_H1  127232               // 8448
#define OFF_X   135680               // 16*EPAD*2 = 4352
#define OFF_G   140032               // 4*16*17*4 = 4352
#define OFF_STG 144384               // 16*16*2   = 512
#define OFF_B0  144896               // 64*4
#define OFF_B1  145152               // 64*4
#define SMEM_TOTAL 145408            // ~142 KiB <= 160 KiB

// Exchange state in module globals.
// Layout: slice-major [parity][g][s][m][4 u64] -> each wg owns a private,
// contiguous 512B block per parity (no inter-wg cacheline sharing on stores).
__device__ u64 g_exch0[2 * NG * NS * MB * 4];   // 256 KiB
__device__ u64 g_exch1[2 * NG * NS * MB * 4];   // 256 KiB
// One 64B cacheline PER flag: flag(g,s) at [(g*NS+s)*16].
__device__ int g_flags0[NG * NS * 16];
__device__ int g_flags1[NG * NS * 16];
__device__ int g_isF32;                     // dtype flag set by probe

__device__ __forceinline__ float bf2f(u16 u) {
  union { u32 i; float f; } v; v.i = ((u32)u) << 16; return v.f;
}
__device__ __forceinline__ u16 f2bf(float f) {
  union { u32 i; float f; } v; v.f = f;
  u32 r = v.i + 0x7fffu + ((v.i >> 16) & 1u);  // round-nearest-even
  return (u16)(r >> 16);
}
__device__ __forceinline__ float sigmoidf_(float x) { return 1.f / (1.f + __expf(-x)); }

// ---- dtype probe: f32 data read as u16 has ~25% "huge bf16" halves; real bf16
// weights (sigma~0.09) have none. Also zeroes the sync flags each call. ----
extern "C" __global__ void dtype_probe(const void* W0v) {
  __shared__ int cntBig;
  if (threadIdx.x == 0) cntBig = 0;
  __syncthreads();
  const u16* u = (const u16*)W0v;
  int big = 0;
  for (int i = threadIdx.x; i < 4096; i += 256)
    if ((u[i] & 0x7F80u) >= 0x4100u) big++;   // |decode| >= 8
  atomicAdd(&cntBig, big);
  __syncthreads();
  for (int i = threadIdx.x; i < NG * NS * 16; i += 256) { g_flags0[i] = 0; g_flags1[i] = 0; }
  if (threadIdx.x == 0) g_isF32 = (cntBig > 100) ? 1 : 0;
}

// ---- inter-workgroup exchange (agent scope => correct across XCDs) ----
// post: wave 0 writes the wg's private 512B block (lane-contiguous, coalesced),
// release-fences its stores, lane 0 stores the flag (own 64B line). No RMW.
__device__ __forceinline__ void postSlice(u64* __restrict__ exch, int* __restrict__ flags,
                                          int t, int g, int s, int tid,
                                          const u16* __restrict__ stg) {
  const int p = t & 1;
  const u64 base = (u64)(((p * NG + g) * NS + s) * MB) * 4;
  if (tid < 64) {
    int m = tid >> 2, j = tid & 3;                  // lane = m*4+j -> contiguous
    u64 v = *(const u64*)(stg + (m << 4) + (j << 2));
    __hip_atomic_store(exch + base + tid, v,
                       __ATOMIC_RELAXED, __HIP_MEMORY_SCOPE_AGENT);
    __builtin_amdgcn_fence(__ATOMIC_RELEASE, "agent");
    if (tid == 0)
      __hip_atomic_store(flags + (g * NS + s) * 16, t + 1,
                         __ATOMIC_RELAXED, __HIP_MEMORY_SCOPE_AGENT);
  }
}

// wait: lanes 0-15 poll 16 separate cachelines (one 16-lane stride-64B load),
// relaxed; single block-wide acquire fence after the rendezvous.
__device__ __forceinline__ void waitFlags(int* __restrict__ flags, int g, int target,
                                          int tid, int* abortF) {
  if (tid < 16 && !(*abortF)) {
    int cap = 500000;   // safety: convert deadlock into fast wrong-answer, not a hang
    while (__hip_atomic_load(flags + (g * NS + tid) * 16,
                             __ATOMIC_RELAXED, __HIP_MEMORY_SCOPE_AGENT) < target) {
      __builtin_amdgcn_s_sleep(4);   // ~256 cyc: don't hammer lines writers need
      if (--cap <= 0) { *abortF = 1; break; }
    }
  }
  __syncthreads();
  __builtin_amdgcn_fence(__ATOMIC_ACQUIRE, "agent");
}

// readback: thread tid -> slice s'=tid>>4, row m'=tid&15; reads 32B contiguous;
// per wave = one 512B contiguous slice block. Scatter into ldsH at col s'*16.
__device__ __forceinline__ void readback(const u64* __restrict__ exch, int t, int g,
                                         int tid, u16* __restrict__ ldsH) {
  const int p = t & 1;
  const int sp = tid >> 4, mp = tid & 15;
  const u64 base = (u64)(((p * NG + g) * NS + sp) * MB + mp) * 4;
#pragma unroll
  for (int j = 0; j < 4; j++) {
    u64 v = __hip_atomic_load(exch + base + j,
                              __ATOMIC_RELAXED, __HIP_MEMORY_SCOPE_AGENT);
    *(u64*)(ldsH + mp * HS + (sp << 4) + (j << 2)) = v;
  }
  __syncthreads();
}

extern "C" __global__ void __launch_bounds__(256)
lstm_fused(const int* __restrict__ tokens, const void* __restrict__ emb,
           const void* __restrict__ W0, const void* __restrict__ R0, const void* __restrict__ b0,
           const void* __restrict__ W1, const void* __restrict__ R1, const void* __restrict__ b1,
           const void* __restrict__ Wout, const void* __restrict__ bout,
           void* __restrict__ outv) {
  extern __shared__ char smem[];
  u16* w0t   = (u16*)(smem + OFF_W0T);
  u16* r0t   = (u16*)(smem + OFF_R0T);
  u16* w1t   = (u16*)(smem + OFF_W1T);
  u16* r1t   = (u16*)(smem + OFF_R1T);
  u16* ldsH0 = (u16*)(smem + OFF_H0);
  u16* ldsH1 = (u16*)(smem + OFF_H1);
  u16* ldsX  = (u16*)(smem + OFF_X);
  float* ldsG = (float*)(smem + OFF_G);
  u16* stg   = (u16*)(smem + OFF_STG);
  float* ldsB0 = (float*)(smem + OFF_B0);
  float* ldsB1 = (float*)(smem + OFF_B1);
  __shared__ int abortF;

  const int tid = threadIdx.x;
  const int g = blockIdx.x & (NG - 1);   // group (all 16 wgs of g land on XCD g%8)
  const int s = blockIdx.x >> 4;         // unit slice
  const int isF32 = g_isF32;             // wave-uniform (probe ran first)

  if (tid == 0) abortF = 0;

  auto ldf = [&](const void* p, int idx) -> float {
    return isF32 ? ((const float*)p)[idx] : bf2f(((const u16*)p)[idx]);
  };

  // ---- one-time: load transposed weight slices into LDS (as bf16) ----
  for (int i = tid; i < 64 * E_SZ; i += 256) {
    int k = i >> 6, n = i & 63;
    int col = ((n >> 4) << 8) + (s << 4) + (n & 15);
    w0t[n * EPAD + k] = f2bf(ldf(W0, k * 1024 + col));
  }
  for (int i = tid; i < 64 * U_SZ; i += 256) {
    int k = i >> 6, n = i & 63;
    int col = ((n >> 4) << 8) + (s << 4) + (n & 15);
    r0t[n * HS + k] = f2bf(ldf(R0, k * 1024 + col));
    w1t[n * HS + k] = f2bf(ldf(W1, k * 1024 + col));
    r1t[n * HS + k] = f2bf(ldf(R1, k * 1024 + col));
  }
  if (tid < 64) {
    int col = ((tid >> 4) << 8) + (s << 4) + (tid & 15);
    ldsB0[tid] = ldf(b0, col);
    ldsB1[tid] = ldf(b1, col);
  }
  for (int i = tid; i < MB * U_SZ; i += 256) {
    int m = i >> 8, k = i & 255;
    ldsH0[m * HS + k] = 0;
    ldsH1[m * HS + k] = 0;
  }

  const int lane = tid & 63;
  const int wv = tid >> 6;       // wave id == gate q (i,f,g,o)
  const int ml = lane & 15;
  const int quad = lane >> 4;
  const int um = tid >> 4;       // update phase: batch row
  const int un = tid & 15;       // update phase: unit within slice

  float c0 = 0.f, c1 = 0.f;
  const int tokBase = (g * MB + um) * T_STEPS;

  // prefetch x_0 into registers
  float4 xfA, xfB; uint4 xbf;
  {
    int tok = tokens[tokBase + 0];
    if (isF32) {
      const float* row = (const float*)emb + (u64)tok * E_SZ + (un << 3);
      xfA = *(const float4*)row; xfB = *(const float4*)(row + 4);
    } else {
      xbf = *(const uint4*)((const u16*)emb + (u64)tok * E_SZ + (un << 3));
    }
  }
  __syncthreads();

  for (int t = 0; t < T_STEPS; t++) {
    // A: commit prefetched x_t to LDS (bf16)
    {
      uint4 pk;
      if (isF32) {
        pk.x = (u32)f2bf(xfA.x) | ((u32)f2bf(xfA.y) << 16);
        pk.y = (u32)f2bf(xfA.z) | ((u32)f2bf(xfA.w) << 16);
        pk.z = (u32)f2bf(xfB.x) | ((u32)f2bf(xfB.y) << 16);
        pk.w = (u32)f2bf(xfB.z) | ((u32)f2bf(xfB.w) << 16);
      } else pk = xbf;
      *(uint4*)(ldsX + um * EPAD + (un << 3)) = pk;
    }
    __syncthreads();

    // B: z0 = b0 + x@W0 + h0_{t-1}@R0 ; gates0
    {
      float bias = ldsB0[(wv << 4) + ml];
      f32x4 acc = {bias, bias, bias, bias};
      const u16* ar = ldsX + ml * EPAD + (quad << 3);
      const u16* br = w0t + ((wv << 4) + ml) * EPAD + (quad << 3);
#pragma unroll
      for (int kc = 0; kc < 4; kc++) {
        bf16x8 av = *(const bf16x8*)(ar + kc * 32);
        bf16x8 bv = *(const bf16x8*)(br + kc * 32);
        acc = __builtin_amdgcn_mfma_f32_16x16x32_bf16(av, bv, acc, 0, 0, 0);
      }
      const u16* ar2 = ldsH0 + ml * HS + (quad << 3);
      const u16* br2 = r0t + ((wv << 4) + ml) * HS + (quad << 3);
#pragma unroll
      for (int kc = 0; kc < 8; kc++) {
        bf16x8 av = *(const bf16x8*)(ar2 + kc * 32);
        bf16x8 bv = *(const bf16x8*)(br2 + kc * 32);
        acc = __builtin_amdgcn_mfma_f32_16x16x32_bf16(av, bv, acc, 0, 0, 0);
      }
#pragma unroll
      for (int r = 0; r < 4; r++) {   // C/D: col=lane&15, row=quad*4+r
        float v = acc[r];
        float gv = (wv == 2) ? tanhf(v) : sigmoidf_(v);
        ldsG[((wv << 4) + (quad << 2) + r) * 17 + ml] = gv;
      }
    }
    __syncthreads();

    // cell update layer 0 -> stg
    {
      float iv = ldsG[um * 17 + un];
      float fv = ldsG[(16 + um) * 17 + un];
      float gv = ldsG[(32 + um) * 17 + un];
      float ov = ldsG[(48 + um) * 17 + un];
      c0 = fv * c0 + iv * gv;
      stg[(um << 4) + un] = f2bf(ov * tanhf(c0));
    }
    __syncthreads();

    // C: post h0_t
    postSlice(g_exch0, g_flags0, t, g, s, tid, stg);

    // issue x_{t+1} prefetch (in flight across waits below)
    if (t + 1 < T_STEPS) {
      int tok = tokens[tokBase + t + 1];
      if (isF32) {
        const float* row = (const float*)emb + (u64)tok * E_SZ + (un << 3);
        xfA = *(const float4*)row; xfB = *(const float4*)(row + 4);
      } else {
        xbf = *(const uint4*)((const u16*)emb + (u64)tok * E_SZ + (un << 3));
      }
    }

    // D: h1_{t-1} (posted last iter, usually ready) + R1 partial — hides h0 wait
    if (t > 0) {
      waitFlags(g_flags1, g, t, tid, &abortF);
      readback(g_exch1, t - 1, g, tid, ldsH1);
    }
    float bias1 = ldsB1[(wv << 4) + ml];
    f32x4 acc1 = {bias1, bias1, bias1, bias1};
    {
      const u16* ar2 = ldsH1 + ml * HS + (quad << 3);
      const u16* br2 = r1t + ((wv << 4) + ml) * HS + (quad << 3);
#pragma unroll
      for (int kc = 0; kc < 8; kc++) {
        bf16x8 av = *(const bf16x8*)(ar2 + kc * 32);
        bf16x8 bv = *(const bf16x8*)(br2 + kc * 32);
        acc1 = __builtin_amdgcn_mfma_f32_16x16x32_bf16(av, bv, acc1, 0, 0, 0);
      }
    }

    // E: rendezvous on h0_t
    waitFlags(g_flags0, g, t + 1, tid, &abortF);
    readback(g_exch0, t, g, tid, ldsH0);

    // F: acc1 += h0_t@W1 ; gates1
    {
      const u16* ar = ldsH0 + ml * HS + (quad << 3);
      const u16* br = w1t + ((wv << 4) + ml) * HS + (quad << 3);
#pragma unroll
      for (int kc = 0; kc < 8; kc++) {
        bf16x8 av = *(const bf16x8*)(ar + kc * 32);
        bf16x8 bv = *(const bf16x8*)(br + kc * 32);
        acc1 = __builtin_amdgcn_mfma_f32_16x16x32_bf16(av, bv, acc1, 0, 0, 0);
      }
#pragma unroll
      for (int r = 0; r < 4; r++) {
        float v = acc1[r];
        float gv = (wv == 2) ? tanhf(v) : sigmoidf_(v);
        ldsG[((wv << 4) + (quad << 2) + r) * 17 + ml] = gv;
      }
    }
    __syncthreads();

    // cell update layer 1 -> stg
    {
      float iv = ldsG[um * 17 + un];
      float fv = ldsG[(16 + um) * 17 + un];
      float gv = ldsG[(32 + um) * 17 + un];
      float ov = ldsG[(48 + um) * 17 + un];
      c1 = fv * c1 + iv * gv;
      stg[(um << 4) + un] = f2bf(ov * tanhf(c1));
    }
    __syncthreads();

    // G: post h1_t (wait deferred to next iter's phase D)
    postSlice(g_exch1, g_flags1, t, g, s, tid, stg);
  }

  // ---- epilogue: logits = h1_final @ Wout + bout; sigmoid ----
  if (s == 0) {
    waitFlags(g_flags1, g, T_STEPS, tid, &abortF);
    readback(g_exch1, T_STEPS - 1, g, tid, ldsH1);
    float* woutf = ldsG;          // 256 floats
    float* red = ldsG + 272;      // 16x17 partials
    woutf[tid] = ldf(Wout, tid);
    __syncthreads();
    float p = 0.f;
#pragma unroll
    for (int j = 0; j < 16; j++)
      p += bf2f(ldsH1[um * HS + (un << 4) + j]) * woutf[(un << 4) + j];
    red[um * 17 + un] = p;
    __syncthreads();
    if (tid < 16) {
      float sum = ldf(bout, 0);
#pragma unroll
      for (int j = 0; j < 16; j++) sum += red[tid * 17 + j];
      float val = sigmoidf_(sum);
      if (isF32) ((float*)outv)[g * MB + tid] = val;
      else       ((u16*)outv)[g * MB + tid] = f2bf(val);
    }
  }
}

extern "C" void kernel_launch(void* const* d_in, const int* in_sizes, int n_in,
                              void* d_out, int out_size, void* d_ws, size_t ws_size,
                              hipStream_t stream) {
  const int* tokens = (const int*)d_in[0];
  const void* emb  = d_in[1];
  const void* W0   = d_in[2];
  const void* R0   = d_in[3];
  const void* b0   = d_in[4];
  const void* W1   = d_in[5];
  const void* R1   = d_in[6];
  const void* b1   = d_in[7];
  const void* Wout = d_in[8];
  const void* bout = d_in[9];

  hipFuncSetAttribute((const void*)lstm_fused,
                      hipFuncAttributeMaxDynamicSharedMemorySize, SMEM_TOTAL);

  // probe: detects f32-vs-bf16 storage, zeroes sync flags (stream-ordered)
  dtype_probe<<<dim3(1), dim3(256), 0, stream>>>(W0);

  // grid = 256 wgs, 142 KiB LDS each -> exactly 1 wg/CU on 256 CUs: co-resident.
  lstm_fused<<<dim3(256), dim3(256), SMEM_TOTAL, stream>>>(
      tokens, emb, W0, R0, b0, W1, R1, b1, Wout, bout, d_out);
}

// Round 6
// 9902.292 us; speedup vs baseline: 2.5370x; 2.5370x over previous
//
#include <hip/hip_runtime.h>

typedef unsigned short u16;
typedef unsigned int u32;
typedef unsigned long long u64;
typedef __attribute__((ext_vector_type(8))) short bf16x8;   // 8 bf16 (4 VGPRs)
typedef __attribute__((ext_vector_type(4))) float f32x4;

#define T_STEPS 1024
#define E_SZ 128
#define U_SZ 256

#define NG 16    // batch groups (16 batches each)
#define MB 16    // batch rows per group
#define NSL 8    // slices per layer (8 L0-wgs + 8 L1-wgs per group)
#define RD 8     // h0 ring depth (L0 may run up to RD-1 steps ahead of L1)
#define HS 264   // padded LDS row stride, K=256
#define EPAD 136 // padded LDS row stride, K=128

// ---- LDS layout (role-dependent), bytes ----
// L0: w0t[128][136] 34816 | r0t[128][264] 67584 | ldsX 4352 | h0f 8448 |
//     G 8704 | stg 1024 | B 512   (end 125440)
#define L0_W0T 0
#define L0_R0T 34816
#define L0_X   102400
#define L0_H0F 106752
#define L0_G   115200
#define L0_STG 123904
#define L0_B   124928
// L1: w1t[128][264] 67584 | r1t 67584 | h0f 8448 | h1p 8448 | G 8704 |
//     stg 1024 | B 512   (end 162304)
#define L1_W1T 0
#define L1_R1T 67584
#define L1_H0F 135168
#define L1_H1P 143616
#define L1_G   152064
#define L1_STG 160768
#define L1_B   161792
#define SMEM_TOTAL 162304   // <= 163840

// ---- exchange state (module globals) ----
__device__ u64 g_exH0[RD * NG * NSL * 128];  // 1 MiB: h0 ring, 1KB/slice-block
__device__ u64 g_exH1[2 * NG * NSL * 128];   // 256 KiB: h1 parity ring
__device__ int g_f0[NG * NSL * 16];          // h0 flags, one 64B line each
__device__ int g_f1[NG * NSL * 16];          // h1 flags
__device__ int g_pr[NG * NSL * 16];          // L1 per-wg consume progress (ring guard)
__device__ int g_isF32;

__device__ __forceinline__ float bf2f(u16 u) {
  union { u32 i; float f; } v; v.i = ((u32)u) << 16; return v.f;
}
__device__ __forceinline__ u16 f2bf(float f) {
  union { u32 i; float f; } v; v.f = f;
  u32 r = v.i + 0x7fffu + ((v.i >> 16) & 1u);
  return (u16)(r >> 16);
}
__device__ __forceinline__ float sig_(float x) { return 1.f / (1.f + __expf(-x)); }
__device__ __forceinline__ float tnh_(float x) { return 2.f / (1.f + __expf(-2.f * x)) - 1.f; }

// ---- dtype probe: also zeroes all sync flags each call ----
extern "C" __global__ void dtype_probe(const void* W0v) {
  __shared__ int cntBig;
  if (threadIdx.x == 0) cntBig = 0;
  __syncthreads();
  const u16* u = (const u16*)W0v;
  int big = 0;
  for (int i = threadIdx.x; i < 4096; i += 256)
    if ((u[i] & 0x7F80u) >= 0x4100u) big++;
  atomicAdd(&cntBig, big);
  __syncthreads();
  for (int i = threadIdx.x; i < NG * NSL * 16; i += 256) {
    g_f0[i] = 0; g_f1[i] = 0; g_pr[i] = 0;
  }
  if (threadIdx.x == 0) g_isF32 = (cntBig > 100) ? 1 : 0;
}

// ---- sync primitives (agent scope; data loads are uncached so no HW acquire
// fence needed — flag observe -> branch -> dependent loads read coherence pt) ----
__device__ __forceinline__ void waitF8(int* __restrict__ flags, int g, int target,
                                       int tid, int* abortF) {
  if (tid < 8 && !(*abortF)) {
    int it = 0;
    while (__hip_atomic_load(flags + ((g << 3) + tid) * 16,
                             __ATOMIC_RELAXED, __HIP_MEMORY_SCOPE_AGENT) < target) {
      if (++it > 200000) { *abortF = 1; break; }
      if (it > 32) __builtin_amdgcn_s_sleep(2);   // hot-poll first ~32 iters
    }
  }
  __syncthreads();
  __atomic_signal_fence(__ATOMIC_ACQUIRE);   // compiler-only; HW order via dep
}

// post one 1KB slice block (wave 0): 2 u64/lane, release fence, flag store
__device__ __forceinline__ void postBlk(u64* __restrict__ exch, u64 blk,
                                        int* __restrict__ flags, int fidx, int val,
                                        int tid, const u16* __restrict__ stg) {
  if (tid < 64) {
    const u64* sp = (const u64*)stg;
    u64 base = blk * 128;
    __hip_atomic_store(exch + base + (tid << 1), sp[tid << 1],
                       __ATOMIC_RELAXED, __HIP_MEMORY_SCOPE_AGENT);
    __hip_atomic_store(exch + base + (tid << 1) + 1, sp[(tid << 1) + 1],
                       __ATOMIC_RELAXED, __HIP_MEMORY_SCOPE_AGENT);
    __builtin_amdgcn_fence(__ATOMIC_RELEASE, "agent");
    if (tid == 0)
      __hip_atomic_store(flags + fidx * 16, val,
                         __ATOMIC_RELAXED, __HIP_MEMORY_SCOPE_AGENT);
  }
}

// gather all 8 slice blocks (8KB) of a slot into ldsH[m*HS + unit]
__device__ __forceinline__ void readBlks(const u64* __restrict__ exch, u64 slot0,
                                         int tid, u16* __restrict__ ldsH) {
  const int sp = tid >> 5, q2 = tid & 31;
  const u64 base = (slot0 + sp) * 128 + (q2 << 2);
  const int m = q2 >> 1, half = q2 & 1;
#pragma unroll
  for (int j = 0; j < 4; j++) {
    u64 v = __hip_atomic_load(exch + base + j,
                              __ATOMIC_RELAXED, __HIP_MEMORY_SCOPE_AGENT);
    *(u64*)(ldsH + m * HS + (sp << 5) + (half << 4) + (j << 2)) = v;
  }
}

extern "C" __global__ void __launch_bounds__(256)
lstm_fused(const int* __restrict__ tokens, const void* __restrict__ emb,
           const void* __restrict__ W0, const void* __restrict__ R0, const void* __restrict__ b0,
           const void* __restrict__ W1, const void* __restrict__ R1, const void* __restrict__ b1,
           const void* __restrict__ Wout, const void* __restrict__ bout,
           void* __restrict__ outv) {
  extern __shared__ char smem[];
  __shared__ int abortF;

  const int tid = threadIdx.x;
  const int b = blockIdx.x;
  const int g = b & (NG - 1);          // group; wgs of g stay on XCD g%8
  const int w = b >> 4;
  const int role = w >> 3;             // 0 = layer-0 wg, 1 = layer-1 wg
  const int sl = w & 7;                // slice: owns units [sl*32, sl*32+32)
  const int isF32 = g_isF32;

  if (tid == 0) abortF = 0;

  auto ldf = [&](const void* p, int idx) -> float {
    return isF32 ? ((const float*)p)[idx] : bf2f(((const u16*)p)[idx]);
  };

  const int lane = tid & 63;
  const int wv = tid >> 6;            // wave = gate q (tiles 2wv, 2wv+1)
  const int ml = lane & 15;
  const int quad = lane >> 4;
  const int um = tid >> 4;            // x-gather: batch row
  const int un = tid & 15;

  if (role == 0) {
    // ================= LAYER-0 WORKGROUP =================
    u16* w0t = (u16*)(smem + L0_W0T);
    u16* r0t = (u16*)(smem + L0_R0T);
    u16* ldsX = (u16*)(smem + L0_X);
    u16* h0f = (u16*)(smem + L0_H0F);
    float* ldsG = (float*)(smem + L0_G);
    u16* stg = (u16*)(smem + L0_STG);
    float* ldsB = (float*)(smem + L0_B);

    // stage weights: cols n<128 = gate(n>>5)*256 + sl*32 + (n&31)
    for (int i = tid; i < 128 * 128; i += 256) {
      int k = i >> 7, n = i & 127;
      int col = ((n >> 5) << 8) + (sl << 5) + (n & 31);
      w0t[n * EPAD + k] = f2bf(ldf(W0, k * 1024 + col));
    }
    for (int i = tid; i < 128 * 256; i += 256) {
      int k = i >> 7, n = i & 127;
      int col = ((n >> 5) << 8) + (sl << 5) + (n & 31);
      r0t[n * HS + k] = f2bf(ldf(R0, k * 1024 + col));
    }
    if (tid < 128) {
      int col = ((tid >> 5) << 8) + (sl << 5) + (tid & 31);
      ldsB[tid] = ldf(b0, col);
    }
    for (int i = tid; i < MB * U_SZ; i += 256) {   // h0_{-1} = 0
      int m = i >> 8, k = i & 255;
      h0f[m * HS + k] = 0;
    }

    float cst[2] = {0.f, 0.f};
    const int tokBase = (g * MB + um) * T_STEPS;

    float4 xfA, xfB; uint4 xbf;
    {
      int tok = tokens[tokBase];
      if (isF32) {
        const float* row = (const float*)emb + (u64)tok * E_SZ + (un << 3);
        xfA = *(const float4*)row; xfB = *(const float4*)(row + 4);
      } else {
        xbf = *(const uint4*)((const u16*)emb + (u64)tok * E_SZ + (un << 3));
      }
    }
    __syncthreads();

    for (int t = 0; t < T_STEPS; t++) {
      // commit x_t
      {
        uint4 pk;
        if (isF32) {
          pk.x = (u32)f2bf(xfA.x) | ((u32)f2bf(xfA.y) << 16);
          pk.y = (u32)f2bf(xfA.z) | ((u32)f2bf(xfA.w) << 16);
          pk.z = (u32)f2bf(xfB.x) | ((u32)f2bf(xfB.y) << 16);
          pk.w = (u32)f2bf(xfB.z) | ((u32)f2bf(xfB.w) << 16);
        } else pk = xbf;
        *(uint4*)(ldsX + um * EPAD + (un << 3)) = pk;
      }
      __syncthreads();

      // z0 = b + x@W0s + h0_{t-1}@R0s  (wave wv: tiles 2wv,2wv+1 = gate wv)
      {
        int row0 = (wv << 5) + ml;
        float ba = ldsB[row0], bb = ldsB[row0 + 16];
        f32x4 acA = {ba, ba, ba, ba}, acB = {bb, bb, bb, bb};
        const u16* ar = ldsX + ml * EPAD + (quad << 3);
        const u16* brA = w0t + row0 * EPAD + (quad << 3);
        const u16* brB = brA + (EPAD << 4);
#pragma unroll
        for (int kc = 0; kc < 4; kc++) {
          bf16x8 av = *(const bf16x8*)(ar + kc * 32);
          acA = __builtin_amdgcn_mfma_f32_16x16x32_bf16(av, *(const bf16x8*)(brA + kc * 32), acA, 0, 0, 0);
          acB = __builtin_amdgcn_mfma_f32_16x16x32_bf16(av, *(const bf16x8*)(brB + kc * 32), acB, 0, 0, 0);
        }
        const u16* ar2 = h0f + ml * HS + (quad << 3);
        const u16* brA2 = r0t + row0 * HS + (quad << 3);
        const u16* brB2 = brA2 + (HS << 4);
#pragma unroll
        for (int kc = 0; kc < 8; kc++) {
          bf16x8 av = *(const bf16x8*)(ar2 + kc * 32);
          acA = __builtin_amdgcn_mfma_f32_16x16x32_bf16(av, *(const bf16x8*)(brA2 + kc * 32), acA, 0, 0, 0);
          acB = __builtin_amdgcn_mfma_f32_16x16x32_bf16(av, *(const bf16x8*)(brB2 + kc * 32), acB, 0, 0, 0);
        }
#pragma unroll
        for (int r = 0; r < 4; r++) {
          int m = (quad << 2) + r;
          float gA = (wv == 2) ? tnh_(acA[r]) : sig_(acA[r]);
          float gB = (wv == 2) ? tnh_(acB[r]) : sig_(acB[r]);
          ldsG[row0 * 17 + m] = gA;
          ldsG[(row0 + 16) * 17 + m] = gB;
        }
      }
      __syncthreads();

      // cell update (2 per thread) -> stg
#pragma unroll
      for (int j = 0; j < 2; j++) {
        int idx = tid + (j << 8);
        int m = idx >> 5, uu = idx & 31;
        float iv = ldsG[uu * 17 + m];
        float fv = ldsG[(32 + uu) * 17 + m];
        float gv = ldsG[(64 + uu) * 17 + m];
        float ov = ldsG[(96 + uu) * 17 + m];
        float c = fv * cst[j] + iv * gv; cst[j] = c;
        stg[(m << 5) + uu] = f2bf(ov * tnh_(c));
      }
      __syncthreads();

      // ring guard: L1 wg sl' must have consumed slot t-RD (prog >= t-RD+1)
      if (t >= RD) waitF8(g_pr, g, t - RD + 1, tid, &abortF);

      // post h0_t into ring slot t%RD
      postBlk(g_exH0, (u64)(((t & (RD - 1)) * NG + g) * NSL + sl),
              g_f0, (g << 3) + sl, t + 1, tid, stg);

      // x_{t+1} prefetch in flight across the rendezvous
      if (t + 1 < T_STEPS) {
        int tok = tokens[tokBase + t + 1];
        if (isF32) {
          const float* row = (const float*)emb + (u64)tok * E_SZ + (un << 3);
          xfA = *(const float4*)row; xfB = *(const float4*)(row + 4);
        } else {
          xbf = *(const uint4*)((const u16*)emb + (u64)tok * E_SZ + (un << 3));
        }
      }

      // rendezvous: all 8 peer slices of h0_t, gather -> h0f (for step t+1)
      waitF8(g_f0, g, t + 1, tid, &abortF);
      readBlks(g_exH0, (u64)((t & (RD - 1)) * NG + g) * NSL, tid, h0f);
      __syncthreads();
    }
  } else {
    // ================= LAYER-1 WORKGROUP =================
    u16* w1t = (u16*)(smem + L1_W1T);
    u16* r1t = (u16*)(smem + L1_R1T);
    u16* h0f = (u16*)(smem + L1_H0F);
    u16* h1p = (u16*)(smem + L1_H1P);
    float* ldsG = (float*)(smem + L1_G);
    u16* stg = (u16*)(smem + L1_STG);
    float* ldsB = (float*)(smem + L1_B);

    for (int i = tid; i < 128 * 256; i += 256) {
      int k = i >> 7, n = i & 127;
      int col = ((n >> 5) << 8) + (sl << 5) + (n & 31);
      w1t[n * HS + k] = f2bf(ldf(W1, k * 1024 + col));
      r1t[n * HS + k] = f2bf(ldf(R1, k * 1024 + col));
    }
    if (tid < 128) {
      int col = ((tid >> 5) << 8) + (sl << 5) + (tid & 31);
      ldsB[tid] = ldf(b1, col);
    }
    for (int i = tid; i < MB * U_SZ; i += 256) {   // h1_{-1} = 0
      int m = i >> 8, k = i & 255;
      h1p[m * HS + k] = 0;
    }
    __syncthreads();

    float cst[2] = {0.f, 0.f};

    for (int t = 0; t < T_STEPS; t++) {
      // 1: consume h0_t (L0 runs ahead; usually zero wait)
      waitF8(g_f0, g, t + 1, tid, &abortF);
      readBlks(g_exH0, (u64)((t & (RD - 1)) * NG + g) * NSL, tid, h0f);
      __syncthreads();
      if (tid == 0) {   // slot t consumed
        __atomic_signal_fence(__ATOMIC_RELEASE);
        __hip_atomic_store(g_pr + ((g << 3) + sl) * 16, t + 1,
                           __ATOMIC_RELAXED, __HIP_MEMORY_SCOPE_AGENT);
      }

      // 2: h1_{t-1} from peers (posted end of t-1)
      if (t > 0) {
        waitF8(g_f1, g, t, tid, &abortF);
        readBlks(g_exH1, (u64)(((t - 1) & 1) * NG + g) * NSL, tid, h1p);
        __syncthreads();
      }

      // 3: z1 = b + h0_t@W1s + h1_{t-1}@R1s ; gates
      {
        int row0 = (wv << 5) + ml;
        float ba = ldsB[row0], bb = ldsB[row0 + 16];
        f32x4 acA = {ba, ba, ba, ba}, acB = {bb, bb, bb, bb};
        const u16* ar = h0f + ml * HS + (quad << 3);
        const u16* brA = w1t + row0 * HS + (quad << 3);
        const u16* brB = brA + (HS << 4);
#pragma unroll
        for (int kc = 0; kc < 8; kc++) {
          bf16x8 av = *(const bf16x8*)(ar + kc * 32);
          acA = __builtin_amdgcn_mfma_f32_16x16x32_bf16(av, *(const bf16x8*)(brA + kc * 32), acA, 0, 0, 0);
          acB = __builtin_amdgcn_mfma_f32_16x16x32_bf16(av, *(const bf16x8*)(brB + kc * 32), acB, 0, 0, 0);
        }
        const u16* ar2 = h1p + ml * HS + (quad << 3);
        const u16* brA2 = r1t + row0 * HS + (quad << 3);
        const u16* brB2 = brA2 + (HS << 4);
#pragma unroll
        for (int kc = 0; kc < 8; kc++) {
          bf16x8 av = *(const bf16x8*)(ar2 + kc * 32);
          acA = __builtin_amdgcn_mfma_f32_16x16x32_bf16(av, *(const bf16x8*)(brA2 + kc * 32), acA, 0, 0, 0);
          acB = __builtin_amdgcn_mfma_f32_16x16x32_bf16(av, *(const bf16x8*)(brB2 + kc * 32), acB, 0, 0, 0);
        }
#pragma unroll
        for (int r = 0; r < 4; r++) {
          int m = (quad << 2) + r;
          float gA = (wv == 2) ? tnh_(acA[r]) : sig_(acA[r]);
          float gB = (wv == 2) ? tnh_(acB[r]) : sig_(acB[r]);
          ldsG[row0 * 17 + m] = gA;
          ldsG[(row0 + 16) * 17 + m] = gB;
        }
      }
      __syncthreads();

      // 4: cell update -> stg
#pragma unroll
      for (int j = 0; j < 2; j++) {
        int idx = tid + (j << 8);
        int m = idx >> 5, uu = idx & 31;
        float iv = ldsG[uu * 17 + m];
        float fv = ldsG[(32 + uu) * 17 + m];
        float gv = ldsG[(64 + uu) * 17 + m];
        float ov = ldsG[(96 + uu) * 17 + m];
        float c = fv * cst[j] + iv * gv; cst[j] = c;
        stg[(m << 5) + uu] = f2bf(ov * tnh_(c));
      }
      __syncthreads();

      // 5: post h1_t (parity ring; consumed by peers next step)
      postBlk(g_exH1, (u64)(((t & 1) * NG + g) * NSL + sl),
              g_f1, (g << 3) + sl, t + 1, tid, stg);
    }

    // epilogue: logits from h1_{T-1}
    if (sl == 0) {
      waitF8(g_f1, g, T_STEPS, tid, &abortF);
      readBlks(g_exH1, (u64)(((T_STEPS - 1) & 1) * NG + g) * NSL, tid, h1p);
      __syncthreads();
      float* woutf = ldsG;
      float* red = ldsG + 272;
      woutf[tid] = ldf(Wout, tid);
      __syncthreads();
      float p = 0.f;
#pragma unroll
      for (int j = 0; j < 16; j++)
        p += bf2f(h1p[um * HS + (un << 4) + j]) * woutf[(un << 4) + j];
      red[um * 17 + un] = p;
      __syncthreads();
      if (tid < 16) {
        float sum = ldf(bout, 0);
#pragma unroll
        for (int j = 0; j < 16; j++) sum += red[tid * 17 + j];
        float val = sig_(sum);
        if (isF32) ((float*)outv)[g * MB + tid] = val;
        else       ((u16*)outv)[g * MB + tid] = f2bf(val);
      }
    }
  }
}

extern "C" void kernel_launch(void* const* d_in, const int* in_sizes, int n_in,
                              void* d_out, int out_size, void* d_ws, size_t ws_size,
                              hipStream_t stream) {
  const int* tokens = (const int*)d_in[0];
  const void* emb  = d_in[1];
  const void* W0   = d_in[2];
  const void* R0   = d_in[3];
  const void* b0   = d_in[4];
  const void* W1   = d_in[5];
  const void* R1   = d_in[6];
  const void* b1   = d_in[7];
  const void* Wout = d_in[8];
  const void* bout = d_in[9];

  hipFuncSetAttribute((const void*)lstm_fused,
                      hipFuncAttributeMaxDynamicSharedMemorySize, SMEM_TOTAL);

  dtype_probe<<<dim3(1), dim3(256), 0, stream>>>(W0);

  // 256 wgs (16 groups x (8 L0 + 8 L1)), 1 wg/CU: co-resident.
  lstm_fused<<<dim3(256), dim3(256), SMEM_TOTAL, stream>>>(
      tokens, emb, W0, R0, b0, W1, R1, b1, Wout, bout, d_out);
}